// Round 10
// baseline (237.009 us; speedup 1.0000x reference)
//
#include <hip/hip_runtime.h>
#include <stdint.h>

// Super-ko filter for Go. Staging: bool inputs are int32 0/1 (verified r7).
//  0 legal_mask (B,19,19) i32 | 1 capture (B,361,361) i32 | 2 player (B,) i32
//  3 zpos (361,3) i32 | 4 chash (B,) i32 | 5 hist (B,3610) i32
//  6 mcount (B,) i32 | 7 logits (B,19,19) f32 -> out (B,19,19) f32
//
// r9 post-mortem: single 1024-thr block/CU = 16 waves/CU, latency-exposed
// batch loop -> ~67us (2 TB/s). Split: scan 4 blocks/batch @512thr (32
// waves/CU) -> per-(b,q) partials in d_ws; finalize combines + hash table.

#define GO_B     256
#define GO_N2    361
#define GO_M     3610
#define GO_SLABB (GO_N2 * GO_N2 * 4)   // 521284 bytes per batch (int32 mask)
#define NSPLIT   4
#define ATHR     512
#define BTHR     512
#define TBL      1024
#define DEPTH    8

__global__ __launch_bounds__(ATHR, 8)
void scan_kernel(const int* __restrict__ cap,
                 const int* __restrict__ player,
                 const int* __restrict__ zpos,
                 uint32_t*  __restrict__ partial)   // [GO_B][NSPLIT][GO_N2]
{
    __shared__ uint32_t Dl[GO_N2];      // remove-opponent-stone delta
    __shared__ uint32_t capx[GO_N2];    // per-quarter capture-delta accumulator

    const int b   = blockIdx.x >> 2;
    const int q   = blockIdx.x & 3;
    const int tid = threadIdx.x;
    const int p   = player[b];

    for (int i = tid; i < GO_N2; i += ATHR) {
        uint32_t z0 = (uint32_t)zpos[i * 3 + 0];
        uint32_t zo = (uint32_t)zpos[i * 3 + 2 - p];
        Dl[i]   = zo ^ z0;
        capx[i] = 0u;
    }
    __syncthreads();

    // this batch's slab, 16B-aligned chunking (identical mapping to r9)
    uintptr_t p0   = (uintptr_t)cap + (size_t)b * GO_SLABB;
    uintptr_t a0   = p0 & ~(uintptr_t)15;
    const uint32_t lead   = (uint32_t)(p0 - a0);            // 0,4,8,12
    const uint32_t nchunk = (lead + GO_SLABB + 15u) >> 4;   // <= 32582
    const uint32_t nq     = (nchunk + NSPLIT - 1) / NSPLIT;
    const uint32_t c0     = (uint32_t)q * nq;
    const uint32_t c1     = (c0 + nq < nchunk) ? (c0 + nq) : nchunk;
    const uint4* __restrict__ src = (const uint4*)a0;

    for (uint32_t cb = c0; cb < c1; cb += ATHR * DEPTH) {
        uint4 w[DEPTH];                       // static indices only (rule #20)
        #pragma unroll
        for (int k = 0; k < DEPTH; ++k) {
            uint32_t c = cb + (uint32_t)tid + (uint32_t)k * ATHR;
            uint4 z; z.x = 0u; z.y = 0u; z.z = 0u; z.w = 0u;
            w[k] = (c < c1) ? src[c] : z;
        }
        #pragma unroll
        for (int k = 0; k < DEPTH; ++k) {
            uint4 ww = w[k];
            if ((ww.x | ww.y | ww.z | ww.w) == 0u) continue;   // ~92% of chunks
            uint32_t base = (cb + (uint32_t)tid + (uint32_t)k * ATHR) * 16u - lead;
            uint32_t dw[4] = { ww.x, ww.y, ww.z, ww.w };
            #pragma unroll
            for (int d = 0; d < 4; ++d) {
                if (dw[d] != 0u) {
                    uint32_t f = base + (uint32_t)(d * 4);   // byte offset in slab
                    if (f < (uint32_t)GO_SLABB) {            // rejects wrap + tail
                        uint32_t e = f >> 2;
                        uint32_t i = e / 361u;
                        uint32_t j = e - i * 361u;
                        atomicXor(&capx[i], Dl[j]);
                    }
                }
            }
        }
    }
    __syncthreads();

    uint32_t* __restrict__ dst = partial + ((size_t)b * NSPLIT + q) * GO_N2;
    for (int i = tid; i < GO_N2; i += ATHR) dst[i] = capx[i];
}

__global__ __launch_bounds__(BTHR)
void finalize_kernel(const int*      __restrict__ legal,
                     const int*      __restrict__ player,
                     const int*      __restrict__ zpos,
                     const int*      __restrict__ chash,
                     const int*      __restrict__ hist,
                     const int*      __restrict__ mcount,
                     const float*    __restrict__ logits,
                     const uint32_t* __restrict__ partial,
                     float*          __restrict__ out)
{
    __shared__ uint32_t thash[TBL];
    __shared__ int      tidx[TBL];
    __shared__ uint8_t  rep[GO_N2];
    __shared__ uint8_t  leg[GO_N2];

    const int b   = blockIdx.x;
    const int tid = threadIdx.x;
    const int p   = player[b];
    const uint32_t ch = (uint32_t)chash[b];

    for (int s = tid; s < TBL; s += BTHR) tidx[s] = -1;
    for (int i = tid; i < GO_N2; i += BTHR) {
        rep[i] = 0u;
        leg[i] = legal[(size_t)b * GO_N2 + i] != 0;
    }
    __syncthreads();

    // combine partials, compute candidate hashes, insert legal ones
    const uint32_t* __restrict__ pp = partial + (size_t)b * NSPLIT * GO_N2;
    for (int i = tid; i < GO_N2; i += BTHR) {
        uint32_t z0 = (uint32_t)zpos[i * 3 + 0];
        uint32_t zp = (uint32_t)zpos[i * 3 + 1 + p];
        uint32_t cx = pp[i] ^ pp[i + GO_N2] ^ pp[i + 2 * GO_N2] ^ pp[i + 3 * GO_N2];
        uint32_t nh = ch ^ (z0 ^ zp) ^ cx;
        if (leg[i]) {
            uint32_t s = nh & (TBL - 1);
            while (true) {
                int prev = atomicCAS(&tidx[s], -1, i);
                if (prev == -1) { thash[s] = nh; break; }
                s = (s + 1) & (TBL - 1);
            }
        }
    }
    __syncthreads();

    const int mc = mcount[b];
    for (int m = tid; m < mc; m += BTHR) {
        uint32_t h = (uint32_t)hist[(size_t)b * GO_M + m];
        uint32_t s = h & (TBL - 1);
        while (tidx[s] != -1) {
            if (thash[s] == h) rep[tidx[s]] = 1u;
            s = (s + 1) & (TBL - 1);
        }
    }
    __syncthreads();

    for (int i = tid; i < GO_N2; i += BTHR) {
        bool keep = leg[i] && !rep[i];
        out[(size_t)b * GO_N2 + i] =
            keep ? logits[(size_t)b * GO_N2 + i] : -1.0e9f;
    }
}

extern "C" void kernel_launch(void* const* d_in, const int* in_sizes, int n_in,
                              void* d_out, int out_size, void* d_ws, size_t ws_size,
                              hipStream_t stream) {
    const int*   legal  = (const int*)d_in[0];
    const int*   cap    = (const int*)d_in[1];
    const int*   player = (const int*)d_in[2];
    const int*   zpos   = (const int*)d_in[3];
    const int*   chash  = (const int*)d_in[4];
    const int*   hist   = (const int*)d_in[5];
    const int*   mcount = (const int*)d_in[6];
    const float* logits = (const float*)d_in[7];
    float*       outp   = (float*)d_out;
    uint32_t*    part   = (uint32_t*)d_ws;   // 256*4*361*4 B = 1.48 MB

    scan_kernel<<<GO_B * NSPLIT, ATHR, 0, stream>>>(cap, player, zpos, part);
    finalize_kernel<<<GO_B, BTHR, 0, stream>>>(legal, player, zpos, chash,
                                               hist, mcount, logits, part, outp);
}

// Round 12
// 220.429 us; speedup vs baseline: 1.0752x; 1.0752x over previous
//
#include <hip/hip_runtime.h>
#include <stdint.h>

// Super-ko filter for Go. Staging: bool inputs are int32 0/1 (verified r7).
//  0 legal_mask (B,19,19) i32 | 1 capture (B,361,361) i32 | 2 player (B,) i32
//  3 zpos (361,3) i32 | 4 chash (B,) i32 | 5 hist (B,3610) i32
//  6 mcount (B,) i32 | 7 logits (B,19,19) f32 -> out (B,19,19) f32
//
// r10 post-mortem: __launch_bounds__(512,8) capped VGPR at 64 -> compiler
// spilled the 8x uint4 batch (VGPR_Count=32, WRITE_SIZE=52MB, 77us).
// This version: 256-thr blocks, NSPLIT=16 -> each block does EXACTLY ONE
// 8-deep batched pass (no loop), launch_bounds(256,4) caps at 128 VGPR so
// the batch provably fits in registers.

#define GO_B     256
#define GO_N2    361
#define GO_M     3610
#define GO_SLABB (GO_N2 * GO_N2 * 4)   // 521284 bytes per batch (int32 mask)
#define NSPLIT   16
#define ATHR     256
#define BTHR     512
#define TBL      1024
#define DEPTH    8

__global__ __launch_bounds__(ATHR, 4)
void scan_kernel(const int* __restrict__ cap,
                 const int* __restrict__ player,
                 const int* __restrict__ zpos,
                 uint32_t*  __restrict__ partial)   // [GO_B][NSPLIT][GO_N2]
{
    __shared__ uint32_t Dl[GO_N2];      // remove-opponent-stone delta
    __shared__ uint32_t capx[GO_N2];    // per-slice capture-delta accumulator

    const int b   = blockIdx.x >> 4;    // batch
    const int q   = blockIdx.x & 15;    // slice
    const int tid = threadIdx.x;
    const int p   = player[b];

    for (int i = tid; i < GO_N2; i += ATHR) {
        uint32_t z0 = (uint32_t)zpos[i * 3 + 0];
        uint32_t zo = (uint32_t)zpos[i * 3 + 2 - p];
        Dl[i]   = zo ^ z0;
        capx[i] = 0u;
    }
    __syncthreads();

    // this batch's slab, 16B-aligned chunking
    uintptr_t p0   = (uintptr_t)cap + (size_t)b * GO_SLABB;
    uintptr_t a0   = p0 & ~(uintptr_t)15;
    const uint32_t lead   = (uint32_t)(p0 - a0);            // 0,4,8,12
    const uint32_t nchunk = (lead + GO_SLABB + 15u) >> 4;   // <= 32582
    const uint32_t nq     = (nchunk + NSPLIT - 1) / NSPLIT; // <= 2037
    const uint32_t c0     = (uint32_t)q * nq;
    const uint32_t c1     = (c0 + nq < nchunk) ? (c0 + nq) : nchunk;
    const uint4* __restrict__ src = (const uint4*)a0;

    // ONE 8-deep batched pass covers the slice: 256 thr * 8 = 2048 >= 2037.
    uint4 w[DEPTH];                       // static indices only (rule #20)
    #pragma unroll
    for (int k = 0; k < DEPTH; ++k) {
        uint32_t c = c0 + (uint32_t)tid + (uint32_t)k * ATHR;
        uint4 z; z.x = 0u; z.y = 0u; z.z = 0u; z.w = 0u;
        w[k] = (c < c1) ? src[c] : z;
    }
    #pragma unroll
    for (int k = 0; k < DEPTH; ++k) {
        uint4 ww = w[k];
        if ((ww.x | ww.y | ww.z | ww.w) == 0u) continue;   // ~92% of chunks
        uint32_t base = (c0 + (uint32_t)tid + (uint32_t)k * ATHR) * 16u - lead;
        uint32_t dw[4] = { ww.x, ww.y, ww.z, ww.w };
        #pragma unroll
        for (int d = 0; d < 4; ++d) {
            if (dw[d] != 0u) {
                uint32_t f = base + (uint32_t)(d * 4);   // byte offset in slab
                if (f < (uint32_t)GO_SLABB) {            // rejects wrap + tail
                    uint32_t e = f >> 2;
                    uint32_t i = e / 361u;
                    uint32_t j = e - i * 361u;
                    atomicXor(&capx[i], Dl[j]);
                }
            }
        }
    }
    __syncthreads();

    uint32_t* __restrict__ dst = partial + ((size_t)b * NSPLIT + q) * GO_N2;
    for (int i = tid; i < GO_N2; i += ATHR) dst[i] = capx[i];
}

__global__ __launch_bounds__(BTHR)
void finalize_kernel(const int*      __restrict__ legal,
                     const int*      __restrict__ player,
                     const int*      __restrict__ zpos,
                     const int*      __restrict__ chash,
                     const int*      __restrict__ hist,
                     const int*      __restrict__ mcount,
                     const float*    __restrict__ logits,
                     const uint32_t* __restrict__ partial,
                     float*          __restrict__ out)
{
    __shared__ uint32_t thash[TBL];
    __shared__ int      tidx[TBL];
    __shared__ uint8_t  rep[GO_N2];
    __shared__ uint8_t  leg[GO_N2];

    const int b   = blockIdx.x;
    const int tid = threadIdx.x;
    const int p   = player[b];
    const uint32_t ch = (uint32_t)chash[b];

    for (int s = tid; s < TBL; s += BTHR) tidx[s] = -1;
    for (int i = tid; i < GO_N2; i += BTHR) {
        rep[i] = 0u;
        leg[i] = legal[(size_t)b * GO_N2 + i] != 0;
    }
    __syncthreads();

    // combine partials, compute candidate hashes, insert legal ones
    const uint32_t* __restrict__ pp = partial + (size_t)b * NSPLIT * GO_N2;
    for (int i = tid; i < GO_N2; i += BTHR) {
        uint32_t z0 = (uint32_t)zpos[i * 3 + 0];
        uint32_t zp = (uint32_t)zpos[i * 3 + 1 + p];
        uint32_t cx = 0u;
        #pragma unroll
        for (int qq = 0; qq < NSPLIT; ++qq) cx ^= pp[i + qq * GO_N2];
        uint32_t nh = ch ^ (z0 ^ zp) ^ cx;
        if (leg[i]) {
            uint32_t s = nh & (TBL - 1);
            while (true) {
                int prev = atomicCAS(&tidx[s], -1, i);
                if (prev == -1) { thash[s] = nh; break; }
                s = (s + 1) & (TBL - 1);
            }
        }
    }
    __syncthreads();

    const int mc = mcount[b];
    for (int m = tid; m < mc; m += BTHR) {
        uint32_t h = (uint32_t)hist[(size_t)b * GO_M + m];
        uint32_t s = h & (TBL - 1);
        while (tidx[s] != -1) {
            if (thash[s] == h) rep[tidx[s]] = 1u;
            s = (s + 1) & (TBL - 1);
        }
    }
    __syncthreads();

    for (int i = tid; i < GO_N2; i += BTHR) {
        bool keep = leg[i] && !rep[i];
        out[(size_t)b * GO_N2 + i] =
            keep ? logits[(size_t)b * GO_N2 + i] : -1.0e9f;
    }
}

extern "C" void kernel_launch(void* const* d_in, const int* in_sizes, int n_in,
                              void* d_out, int out_size, void* d_ws, size_t ws_size,
                              hipStream_t stream) {
    const int*   legal  = (const int*)d_in[0];
    const int*   cap    = (const int*)d_in[1];
    const int*   player = (const int*)d_in[2];
    const int*   zpos   = (const int*)d_in[3];
    const int*   chash  = (const int*)d_in[4];
    const int*   hist   = (const int*)d_in[5];
    const int*   mcount = (const int*)d_in[6];
    const float* logits = (const float*)d_in[7];
    float*       outp   = (float*)d_out;
    uint32_t*    part   = (uint32_t*)d_ws;   // 256*16*361*4 B = 5.9 MB

    scan_kernel<<<GO_B * NSPLIT, ATHR, 0, stream>>>(cap, player, zpos, part);
    finalize_kernel<<<GO_B, BTHR, 0, stream>>>(legal, player, zpos, chash,
                                               hist, mcount, logits, part, outp);
}